// Round 1
// baseline (389.737 us; speedup 1.0000x reference)
//
#include <hip/hip_runtime.h>
#include <math.h>

#define BB 8
#define TT 64
#define DD 1024
#define SS 32
#define EE 16
#define VV 50257
#define BT (BB*TT)   // 512
#define BS (BB*SS)   // 256

// ---------------------------------------------------------------------------
// Fused GEMM: rows 0..511 -> q = dec@Wq+bq ; rows 512..767 -> k = scene@Wk+bk
// 64x64 tile per block, 256 threads, 4x4 per thread, K-tile 16, f32.
// ---------------------------------------------------------------------------
__global__ __launch_bounds__(256) void gemm_qk(
    const float* __restrict__ dec, const float* __restrict__ scene,
    const float* __restrict__ Wq, const float* __restrict__ bq,
    const float* __restrict__ Wk, const float* __restrict__ bk,
    float* __restrict__ q, float* __restrict__ k)
{
    __shared__ __align__(16) float As[16][68];   // [kk][m], padded
    __shared__ __align__(16) float Bs[16][68];   // [kk][n], padded
    const int bn = blockIdx.x;      // 0..15  (N tiles)
    const int bm = blockIdx.y;      // 0..11  (M tiles; 8 for q, 4 for k)
    const bool isq = (bm < 8);
    const float* X   = isq ? dec : scene;
    const float* W   = isq ? Wq  : Wk;
    const float* bia = isq ? bq  : bk;
    float*       Y   = isq ? q   : k;
    const int row0 = (isq ? bm : bm - 8) * 64;
    const int col0 = bn * 64;
    const int tid = threadIdx.x;
    const int tx = tid & 15, ty = tid >> 4;

    float acc[4][4] = {};
    for (int k0 = 0; k0 < DD; k0 += 16) {
        {   // X tile 64x16 -> As (transposed)
            const int m  = tid >> 2;
            const int kc = (tid & 3) * 4;
            const float4 x4 = *(const float4*)&X[(size_t)(row0 + m) * DD + k0 + kc];
            As[kc + 0][m] = x4.x; As[kc + 1][m] = x4.y;
            As[kc + 2][m] = x4.z; As[kc + 3][m] = x4.w;
        }
        {   // W tile 16x64 -> Bs
            const int kk = tid >> 4;
            const int nc = (tid & 15) * 4;
            *(float4*)&Bs[kk][nc] = *(const float4*)&W[(size_t)(k0 + kk) * DD + col0 + nc];
        }
        __syncthreads();
        #pragma unroll
        for (int kk = 0; kk < 16; ++kk) {
            float a[4], b[4];
            #pragma unroll
            for (int i = 0; i < 4; ++i) a[i] = As[kk][ty * 4 + i];
            #pragma unroll
            for (int j = 0; j < 4; ++j) b[j] = Bs[kk][tx * 4 + j];
            #pragma unroll
            for (int i = 0; i < 4; ++i)
                #pragma unroll
                for (int j = 0; j < 4; ++j)
                    acc[i][j] += a[i] * b[j];
        }
        __syncthreads();
    }
    #pragma unroll
    for (int i = 0; i < 4; ++i) {
        const int r = row0 + ty * 4 + i;
        #pragma unroll
        for (int j = 0; j < 4; ++j) {
            const int c = col0 + tx * 4 + j;
            Y[(size_t)r * DD + c] = acc[i][j] + bia[c];
        }
    }
}

// ---------------------------------------------------------------------------
// Per-row dots with Wp: dw[bt] = dec[bt]·Wp[0:D], mw[bs] = scene[bs]·Wp[D:2D]
// ---------------------------------------------------------------------------
__global__ __launch_bounds__(64) void dots_kernel(
    const float* __restrict__ dec, const float* __restrict__ scene,
    const float* __restrict__ Wp, float* __restrict__ dw, float* __restrict__ mw)
{
    const int b = blockIdx.x;         // 0..767
    const int lane = threadIdx.x;
    const float* x; const float* wp; float* out;
    if (b < BT) { x = dec   + (size_t)b * DD;        wp = Wp;      out = dw + b; }
    else        { x = scene + (size_t)(b - BT) * DD; wp = Wp + DD; out = mw + (b - BT); }
    float s = 0.f;
    #pragma unroll 4
    for (int i = lane; i < DD; i += 64) s += x[i] * wp[i];
    for (int off = 32; off; off >>= 1) s += __shfl_down(s, off);
    if (lane == 0) *out = s;
}

// ---------------------------------------------------------------------------
// Attention + p_gen: one block per (b,t). scores->softmax->attn row, then
// p_gen = sigmoid(10*(dec·Wp0 + sum_s attn_s*mw[b,s] + bp - 0.5))
// ---------------------------------------------------------------------------
__global__ __launch_bounds__(256) void attn_kernel(
    const float* __restrict__ qm, const float* __restrict__ km,
    const float* __restrict__ dwv, const float* __restrict__ mwv,
    const float* __restrict__ bp,
    float* __restrict__ attn_out, float* __restrict__ pgen_out)
{
    __shared__ __align__(16) float qs[DD];
    __shared__ float sc[SS];
    const int bt = blockIdx.x;        // 0..511
    const int b  = bt / TT;
    const int tid = threadIdx.x;
    for (int i = tid; i < DD; i += 256) qs[i] = qm[(size_t)bt * DD + i];
    __syncthreads();
    const int w = tid >> 6, lane = tid & 63;
    for (int j = 0; j < 8; ++j) {             // each wave: 8 of 32 s-values
        const int s = w * 8 + j;
        const float* kr = km + (size_t)(b * SS + s) * DD;
        float acc = 0.f;
        #pragma unroll
        for (int i = 0; i < 16; ++i) acc += qs[lane + 64 * i] * kr[lane + 64 * i];
        for (int off = 32; off; off >>= 1) acc += __shfl_down(acc, off);
        if (lane == 0) sc[s] = acc * 0.03125f;   // 1/sqrt(1024)
    }
    __syncthreads();
    if (tid < 64) {
        float v = (lane < SS) ? sc[lane] : -INFINITY;
        float m = v;
        for (int off = 32; off; off >>= 1) m = fmaxf(m, __shfl_xor(m, off));
        float e = (lane < SS) ? __expf(v - m) : 0.f;
        float sum = e;
        for (int off = 32; off; off >>= 1) sum += __shfl_xor(sum, off);
        const float a = e / sum;
        float g = (lane < SS) ? a * mwv[b * SS + lane] : 0.f;
        for (int off = 32; off; off >>= 1) g += __shfl_xor(g, off);
        if (lane < SS) attn_out[bt * SS + lane] = a;
        if (lane == 0) {
            const float z = dwv[bt] + g + bp[0] - 0.5f;
            pgen_out[bt] = 1.0f / (1.0f + __expf(-10.0f * z));
        }
    }
}

// ---------------------------------------------------------------------------
// Salience: one block per (b,s). 16 gathered-embedding dots, softmax over E,
// then last-write-wins dedup mask (numpy fancy-assignment semantics).
// ---------------------------------------------------------------------------
__global__ __launch_bounds__(256) void sal_kernel(
    const float* __restrict__ dec, const float* __restrict__ emb,
    const int* __restrict__ ids, float* __restrict__ sal)
{
    __shared__ __align__(16) float ds[DD];
    __shared__ float logit[EE];
    __shared__ int lid[EE];
    const int bs = blockIdx.x;        // 0..255
    const int b  = bs / SS;
    const int tid = threadIdx.x;
    const float* dl = dec + (size_t)(b * TT + (TT - 1)) * DD;  // dec_last
    for (int i = tid; i < DD; i += 256) ds[i] = dl[i];
    if (tid < EE) lid[tid] = ids[bs * EE + tid];
    __syncthreads();
    const int w = tid >> 6, lane = tid & 63;
    for (int j = 0; j < 4; ++j) {             // each wave: 4 of 16 e-values
        const int e = w * 4 + j;
        const float* er = emb + (size_t)lid[e] * DD;
        float acc = 0.f;
        #pragma unroll
        for (int i = 0; i < 16; ++i) acc += ds[lane + 64 * i] * er[lane + 64 * i];
        for (int off = 32; off; off >>= 1) acc += __shfl_down(acc, off);
        if (lane == 0) logit[e] = acc;
    }
    __syncthreads();
    if (tid == 0) {
        float m = -INFINITY;
        for (int e = 0; e < EE; ++e) m = fmaxf(m, logit[e]);
        float ex[EE]; float sum = 0.f;
        for (int e = 0; e < EE; ++e) { ex[e] = __expf(logit[e] - m); sum += ex[e]; }
        const float inv = 1.0f / sum;
        for (int e = 0; e < EE; ++e) {
            bool dup = false;
            for (int e2 = e + 1; e2 < EE; ++e2)
                if (lid[e2] == lid[e]) { dup = true; break; }
            sal[bs * EE + e] = dup ? 0.f : ex[e] * inv;
        }
    }
}

// ---------------------------------------------------------------------------
// pointer_probs: one block per (b,t) row. Zero own V-row, then 512 atomic
// scatter-adds into it (fuses the 103 MB zero-fill with the scatter).
// ---------------------------------------------------------------------------
__global__ __launch_bounds__(256) void pp_kernel(
    const float* __restrict__ attn, const float* __restrict__ sal,
    const int* __restrict__ ids, float* __restrict__ pp)
{
    __shared__ float at[SS];
    const int bt = blockIdx.x;        // 0..511
    const int b  = bt / TT;
    const int tid = threadIdx.x;
    if (tid < SS) at[tid] = attn[bt * SS + tid];
    float* row = pp + (size_t)bt * VV;
    for (int i = tid; i < VV; i += 256) row[i] = 0.f;
    __syncthreads();
    for (int i = tid; i < SS * EE; i += 256) {
        const int s = i >> 4, e = i & 15;
        const float v = at[s] * sal[(b * SS + s) * EE + e];
        atomicAdd(&row[ids[(b * SS + s) * EE + e]], v);
    }
}

extern "C" void kernel_launch(void* const* d_in, const int* in_sizes, int n_in,
                              void* d_out, int out_size, void* d_ws, size_t ws_size,
                              hipStream_t stream) {
    (void)in_sizes; (void)n_in; (void)ws_size; (void)out_size;
    const float* dec   = (const float*)d_in[0];
    const float* scene = (const float*)d_in[1];
    const float* emb   = (const float*)d_in[2];
    const int*   ids   = (const int*)  d_in[3];
    const float* Wq    = (const float*)d_in[4];
    const float* bq    = (const float*)d_in[5];
    const float* Wk    = (const float*)d_in[6];
    const float* bk    = (const float*)d_in[7];
    const float* Wp    = (const float*)d_in[8];
    const float* bp    = (const float*)d_in[9];
    float* out = (float*)d_out;          // [0..511] p_gen, then pointer_probs
    float* ws  = (float*)d_ws;

    float* q    = ws;                         // 512*1024
    float* k    = q    + 512 * 1024;          // 256*1024
    float* attn = k    + 256 * 1024;          // 512*32
    float* sal  = attn + 512 * 32;            // 256*16
    float* dw   = sal  + 256 * 16;            // 512
    float* mw   = dw   + 512;                 // 256

    gemm_qk<<<dim3(16, 12), 256, 0, stream>>>(dec, scene, Wq, bq, Wk, bk, q, k);
    dots_kernel<<<768, 64, 0, stream>>>(dec, scene, Wp, dw, mw);
    attn_kernel<<<512, 256, 0, stream>>>(q, k, dw, mw, bp, attn, out);
    sal_kernel<<<256, 256, 0, stream>>>(dec, emb, ids, sal);
    pp_kernel<<<512, 256, 0, stream>>>(attn, sal, ids, out + 512);
}

// Round 2
// 327.084 us; speedup vs baseline: 1.1915x; 1.1915x over previous
//
#include <hip/hip_runtime.h>
#include <hip/hip_bf16.h>
#include <math.h>

#define BB 8
#define TT 64
#define DD 1024
#define SS 32
#define EE 16
#define VV 50257
#define BT (BB*TT)   // 512
#define BS (BB*SS)   // 256

typedef __attribute__((ext_vector_type(8))) short short8;   // 8 bf16 (4 VGPRs)
typedef __attribute__((ext_vector_type(4))) float floatx4;  // 4 fp32

static __device__ inline unsigned short f2bf(float x) {
    __hip_bfloat16 h = __float2bfloat16(x);   // RNE
    union { __hip_bfloat16 h; unsigned short u; } cv; cv.h = h;
    return cv.u;
}

static __device__ inline void gl_lds16(const void* g, void* l) {
    __builtin_amdgcn_global_load_lds(
        (const __attribute__((address_space(1))) void*)g,
        (__attribute__((address_space(3))) void*)l, 16, 0, 0);
}

// ---------------------------------------------------------------------------
// K0 prep:
//  blocks [0,768):    convert dec|scene row -> Xb[row][k] bf16
//  blocks [768,1280): transpose-convert Wq|Wk -> Wt[sel][n][k] bf16 (64x64 tiles)
//  blocks [1280,2048): dots dw[bt]=dec.Wp0, mw[bs]=scene.Wp1 (f32 exact)
// ---------------------------------------------------------------------------
__global__ __launch_bounds__(256) void prep_kernel(
    const float* __restrict__ dec, const float* __restrict__ scene,
    const float* __restrict__ Wq, const float* __restrict__ Wk,
    const float* __restrict__ Wp,
    unsigned short* __restrict__ Xb, unsigned short* __restrict__ Wt,
    float* __restrict__ dw, float* __restrict__ mw)
{
    __shared__ float tile[64][65];
    const int bid = blockIdx.x;
    const int t = threadIdx.x;
    if (bid < 768) {                       // ---- convert X rows
        const int row = bid;
        const float* src = (row < BT) ? dec + (size_t)row * DD
                                      : scene + (size_t)(row - BT) * DD;
        const float4 v = *(const float4*)&src[t * 4];
        ushort4 u;
        u.x = f2bf(v.x); u.y = f2bf(v.y); u.z = f2bf(v.z); u.w = f2bf(v.w);
        *(ushort4*)&Xb[(size_t)row * DD + t * 4] = u;
    } else if (bid < 1280) {               // ---- transpose-convert W
        const int tb = bid - 768;
        const int sel = tb >> 8;           // 0=Wq, 1=Wk
        const int tt8 = tb & 255;
        const int k0 = (tt8 >> 4) * 64, n0 = (tt8 & 15) * 64;
        const float* Wsrc = sel ? Wk : Wq;
        const int c4 = (t & 15) * 4;
        #pragma unroll
        for (int i = 0; i < 4; ++i) {
            const int r = (t >> 4) + 16 * i;
            const float4 v = *(const float4*)&Wsrc[(size_t)(k0 + r) * DD + n0 + c4];
            tile[r][c4 + 0] = v.x; tile[r][c4 + 1] = v.y;
            tile[r][c4 + 2] = v.z; tile[r][c4 + 3] = v.w;
        }
        __syncthreads();
        #pragma unroll
        for (int i = 0; i < 4; ++i) {
            const int n = (t >> 4) + 16 * i;
            ushort4 u;
            u.x = f2bf(tile[c4 + 0][n]); u.y = f2bf(tile[c4 + 1][n]);
            u.z = f2bf(tile[c4 + 2][n]); u.w = f2bf(tile[c4 + 3][n]);
            *(ushort4*)&Wt[(size_t)sel * DD * DD + (size_t)(n0 + n) * DD + k0 + c4] = u;
        }
    } else {                               // ---- Wp dots (f32 exact)
        const int di = bid - 1280;         // 0..767
        const float* x; const float* wp; float* outp;
        if (di < BT) { x = dec   + (size_t)di * DD;        wp = Wp;      outp = dw + di; }
        else         { x = scene + (size_t)(di - BT) * DD; wp = Wp + DD; outp = mw + (di - BT); }
        float s = 0.f;
        #pragma unroll
        for (int i = 0; i < 4; ++i) s += x[t + 256 * i] * wp[t + 256 * i];
        for (int off = 32; off; off >>= 1) s += __shfl_down(s, off);
        if ((t & 63) == 0) tile[0][t >> 6] = s;
        __syncthreads();
        if (t == 0) *outp = tile[0][0] + tile[0][1] + tile[0][2] + tile[0][3];
    }
}

// ---------------------------------------------------------------------------
// K1 MFMA GEMM: Y[768][1024] = Xb @ W(sel by row group), f32 out + bias.
// Block: 128 thr (2 waves), tile 32(M)x64(N), K-step 32. 384 blocks.
// A,B frags both contiguous-k (Wt is [n][k]) -> single ds_read_b128 each.
// ---------------------------------------------------------------------------
__global__ __launch_bounds__(128) void gemm_mfma(
    const unsigned short* __restrict__ Xb, const unsigned short* __restrict__ Wt,
    const float* __restrict__ bq, const float* __restrict__ bk,
    float* __restrict__ qo, float* __restrict__ ko)
{
    __shared__ unsigned short As[32 * 32];   // [m][k] 2 KB
    __shared__ unsigned short Bs[64 * 32];   // [n][k] 4 KB
    const int bid = blockIdx.x;
    const int bm = bid >> 4;                 // 0..23
    const int bn = bid & 15;                 // 0..15
    const int m0 = bm * 32, n0 = bn * 64;
    const bool isq = (bm < 16);
    const unsigned short* Wsel = Wt + (isq ? 0 : (size_t)DD * DD);
    const int tid = threadIdx.x;
    const int w = tid >> 6, l = tid & 63;

    const int arow = 16 * w + (l >> 2);      // staging row (A)
    const int kb8  = (l & 3) * 8;            // staging k offset (elems)
    floatx4 acc[4] = {{0.f,0.f,0.f,0.f},{0.f,0.f,0.f,0.f},
                      {0.f,0.f,0.f,0.f},{0.f,0.f,0.f,0.f}};

    for (int k0 = 0; k0 < DD; k0 += 32) {
        __syncthreads();
        gl_lds16(&Xb[(size_t)(m0 + arow) * DD + k0 + kb8], &As[w * 512]);
        #pragma unroll
        for (int i = 0; i < 2; ++i) {
            const int brow = 32 * w + 16 * i + (l >> 2);
            gl_lds16(&Wsel[(size_t)(n0 + brow) * DD + k0 + kb8],
                     &Bs[w * 1024 + i * 512]);
        }
        __syncthreads();
        const short8 a = *(const short8*)&As[(16 * w + (l & 15)) * 32 + (l >> 4) * 8];
        #pragma unroll
        for (int j = 0; j < 4; ++j) {
            const short8 b = *(const short8*)&Bs[(16 * j + (l & 15)) * 32 + (l >> 4) * 8];
            acc[j] = __builtin_amdgcn_mfma_f32_16x16x32_bf16(a, b, acc[j], 0, 0, 0);
        }
    }
    // C/D: col = lane&15, row = (lane>>4)*4 + reg   [m89-verified]
    #pragma unroll
    for (int j = 0; j < 4; ++j) {
        const int gcol = n0 + 16 * j + (l & 15);
        const float bias = isq ? bq[gcol] : bk[gcol];
        #pragma unroll
        for (int r = 0; r < 4; ++r) {
            const int grow = m0 + 16 * w + (l >> 4) * 4 + r;
            const float val = acc[j][r] + bias;
            if (isq) qo[(size_t)grow * DD + gcol] = val;
            else     ko[(size_t)(grow - BT) * DD + gcol] = val;
        }
    }
}

// ---------------------------------------------------------------------------
// K2: blocks [0,512) attention+p_gen per (b,t); blocks [512,768) salience per (b,s)
// ---------------------------------------------------------------------------
__global__ __launch_bounds__(256) void attn_sal_kernel(
    const float* __restrict__ qm, const float* __restrict__ km,
    const float* __restrict__ dec, const float* __restrict__ emb,
    const int* __restrict__ ids,
    const float* __restrict__ dwv, const float* __restrict__ mwv,
    const float* __restrict__ bp,
    float* __restrict__ attn_out, float* __restrict__ pgen_out,
    float* __restrict__ sal_out)
{
    __shared__ __align__(16) float qs[DD];
    __shared__ float sc[SS];
    __shared__ int lid[EE];
    const int tid = threadIdx.x;
    const int w = tid >> 6, lane = tid & 63;

    if (blockIdx.x < BT) {
        // ---------------- attention + p_gen ----------------
        const int bt = blockIdx.x;
        const int b  = bt / TT;
        *(float4*)&qs[tid * 4] = *(const float4*)&qm[(size_t)bt * DD + tid * 4];
        __syncthreads();
        for (int j = 0; j < 8; ++j) {
            const int s = w * 8 + j;
            const float* kr = km + (size_t)(b * SS + s) * DD;
            float accv = 0.f;
            #pragma unroll
            for (int i = 0; i < 4; ++i) {
                const float4 qv = *(const float4*)&qs[4 * lane + 256 * i];
                const float4 kv = *(const float4*)&kr[4 * lane + 256 * i];
                accv += qv.x * kv.x + qv.y * kv.y + qv.z * kv.z + qv.w * kv.w;
            }
            for (int off = 32; off; off >>= 1) accv += __shfl_down(accv, off);
            if (lane == 0) sc[s] = accv * 0.03125f;
        }
        __syncthreads();
        if (tid < 64) {
            float v = (lane < SS) ? sc[lane] : -INFINITY;
            float m = v;
            for (int off = 32; off; off >>= 1) m = fmaxf(m, __shfl_xor(m, off));
            float e = (lane < SS) ? __expf(v - m) : 0.f;
            float sum = e;
            for (int off = 32; off; off >>= 1) sum += __shfl_xor(sum, off);
            const float a = e / sum;
            float g = (lane < SS) ? a * mwv[b * SS + lane] : 0.f;
            for (int off = 32; off; off >>= 1) g += __shfl_xor(g, off);
            if (lane < SS) attn_out[bt * SS + lane] = a;
            if (lane == 0) {
                const float z = dwv[bt] + g + bp[0] - 0.5f;
                pgen_out[bt] = 1.0f / (1.0f + __expf(-10.0f * z));
            }
        }
    } else {
        // ---------------- salience ----------------
        const int bs = blockIdx.x - BT;     // 0..255
        const int b  = bs / SS;
        const float* dl = dec + (size_t)(b * TT + (TT - 1)) * DD;
        *(float4*)&qs[tid * 4] = *(const float4*)&dl[tid * 4];
        if (tid < EE) lid[tid] = ids[bs * EE + tid];
        __syncthreads();
        for (int j = 0; j < 4; ++j) {
            const int e = w * 4 + j;
            const float* er = emb + (size_t)lid[e] * DD;
            float accv = 0.f;
            #pragma unroll
            for (int i = 0; i < 4; ++i) {
                const float4 dv = *(const float4*)&qs[4 * lane + 256 * i];
                const float4 ev = *(const float4*)&er[4 * lane + 256 * i];
                accv += dv.x * ev.x + dv.y * ev.y + dv.z * ev.z + dv.w * ev.w;
            }
            for (int off = 32; off; off >>= 1) accv += __shfl_down(accv, off);
            if (lane == 0) sc[e] = accv;
        }
        __syncthreads();
        if (tid == 0) {
            float m = -INFINITY;
            for (int e = 0; e < EE; ++e) m = fmaxf(m, sc[e]);
            float ex[EE]; float sum = 0.f;
            for (int e = 0; e < EE; ++e) { ex[e] = __expf(sc[e] - m); sum += ex[e]; }
            const float inv = 1.0f / sum;
            for (int e = 0; e < EE; ++e) {
                bool dup = false;
                for (int e2 = e + 1; e2 < EE; ++e2)
                    if (lid[e2] == lid[e]) { dup = true; break; }
                sal_out[bs * EE + e] = dup ? 0.f : ex[e] * inv;
            }
        }
    }
}

// ---------------------------------------------------------------------------
// K3 pointer_probs: one block per (b,t) row; vectorized zero then scatter.
// ---------------------------------------------------------------------------
__global__ __launch_bounds__(256) void pp_kernel(
    const float* __restrict__ attn, const float* __restrict__ sal,
    const int* __restrict__ ids, float* __restrict__ pp)
{
    __shared__ float at[SS];
    const int bt = blockIdx.x;
    const int b  = bt / TT;
    const int tid = threadIdx.x;
    if (tid < SS) at[tid] = attn[bt * SS + tid];
    float* row = pp + (size_t)bt * VV;
    const int h = (4 - (bt & 3)) & 3;          // scalar head to reach 16B align
    if (tid < h) row[tid] = 0.f;
    const int nv = (VV - h) >> 2;
    float4* rv = (float4*)(row + h);
    const float4 z4 = make_float4(0.f, 0.f, 0.f, 0.f);
    for (int i = tid; i < nv; i += 256) rv[i] = z4;
    const int tail = (VV - h) & 3;
    if (tid < tail) row[h + 4 * nv + tid] = 0.f;
    __syncthreads();
    for (int i = tid; i < SS * EE; i += 256) {
        const int s = i >> 4, e = i & 15;
        const float v = at[s] * sal[(b * SS + s) * EE + e];
        atomicAdd(&row[ids[(b * SS + s) * EE + e]], v);
    }
}

extern "C" void kernel_launch(void* const* d_in, const int* in_sizes, int n_in,
                              void* d_out, int out_size, void* d_ws, size_t ws_size,
                              hipStream_t stream) {
    (void)in_sizes; (void)n_in; (void)ws_size; (void)out_size;
    const float* dec   = (const float*)d_in[0];
    const float* scene = (const float*)d_in[1];
    const float* emb   = (const float*)d_in[2];
    const int*   ids   = (const int*)  d_in[3];
    const float* Wq    = (const float*)d_in[4];
    const float* bq    = (const float*)d_in[5];
    const float* Wk    = (const float*)d_in[6];
    const float* bk    = (const float*)d_in[7];
    const float* Wp    = (const float*)d_in[8];
    const float* bp    = (const float*)d_in[9];
    float* out = (float*)d_out;          // [0..511] p_gen, then pointer_probs
    float* ws  = (float*)d_ws;

    float* q    = ws;                           // 512*1024
    float* kbuf = q    + 512 * 1024;            // 256*1024
    float* attn = kbuf + 256 * 1024;            // 512*32
    float* sal  = attn + 512 * 32;              // 256*16
    float* dw   = sal  + 256 * 16;              // 512
    float* mw   = dw   + 512;                   // 256
    unsigned short* Xb = (unsigned short*)(mw + 256);     // 768*1024 bf16
    unsigned short* Wt = Xb + 768 * 1024;                 // 2*1024*1024 bf16

    prep_kernel<<<2048, 256, 0, stream>>>(dec, scene, Wq, Wk, Wp, Xb, Wt, dw, mw);
    gemm_mfma<<<384, 128, 0, stream>>>(Xb, Wt, bq, bk, q, kbuf);
    attn_sal_kernel<<<768, 256, 0, stream>>>(q, kbuf, dec, emb, ids, dw, mw, bp,
                                             attn, out, sal);
    pp_kernel<<<512, 256, 0, stream>>>(attn, sal, ids, out + 512);
}